// Round 1
// baseline (139.168 us; speedup 1.0000x reference)
//
#include <hip/hip_runtime.h>
#include <hip/hip_bf16.h>

typedef __attribute__((ext_vector_type(4))) float f32x4;
typedef __attribute__((ext_vector_type(8))) short s16x8;
typedef unsigned short u16;
typedef unsigned int u32;

#define ALPHA 1.6986436f          /* sqrt(2*log2(e)) : sim*log2e = dot(a*h, a*h) */
#define LN2F  0.69314718056f

__device__ __forceinline__ u16 f2bf(float x) {
  union { float f; u32 u; } v; v.f = x;
  u32 r = v.u + 0x7fffu + ((v.u >> 16) & 1u);
  return (u16)(r >> 16);
}

#if __has_builtin(__builtin_amdgcn_exp2f)
__device__ __forceinline__ float fexp2(float x) { return __builtin_amdgcn_exp2f(x); }
#else
__device__ __forceinline__ float fexp2(float x) { return exp2f(x); }
#endif
#if __has_builtin(__builtin_amdgcn_logf)
__device__ __forceinline__ float flog2(float x) { return __builtin_amdgcn_logf(x); }
#else
__device__ __forceinline__ float flog2(float x) { return log2f(x); }
#endif

__device__ __forceinline__ f32x4 mfma16(s16x8 a, s16x8 b, f32x4 c) {
  return __builtin_amdgcn_mfma_f32_16x16x32_bf16(a, b, c, 0, 0, 0);
}

__device__ __forceinline__ void gl16(const void* g, void* l) {
  __builtin_amdgcn_global_load_lds(
      (const __attribute__((address_space(1))) u32*)g,
      (__attribute__((address_space(3))) u32*)l, 16, 0, 0);
}

// ---------------- prep: h -> bf16, scaled by ALPHA, swizzled layout ----------
// hbf row r: byte off = r*256 + ((2k) ^ ((r&7)<<4))
__global__ void prep_h(const float* __restrict__ h_i, const float* __restrict__ h_j,
                       u16* __restrict__ hbf) {
  int t = blockIdx.x * 256 + threadIdx.x;       // 131072 threads
  int row = t >> 4, kb = t & 15;
  const float* src = (row < 4096 ? h_i + (size_t)row * 128
                                 : h_j + (size_t)(row - 4096) * 128) + kb * 8;
  float4 f0 = *(const float4*)(src);
  float4 f1 = *(const float4*)(src + 4);
  s16x8 o;
  o[0] = (short)f2bf(ALPHA * f0.x); o[1] = (short)f2bf(ALPHA * f0.y);
  o[2] = (short)f2bf(ALPHA * f0.z); o[3] = (short)f2bf(ALPHA * f0.w);
  o[4] = (short)f2bf(ALPHA * f1.x); o[5] = (short)f2bf(ALPHA * f1.y);
  o[6] = (short)f2bf(ALPHA * f1.z); o[7] = (short)f2bf(ALPHA * f1.w);
  char* dst = (char*)hbf + (size_t)row * 256 + ((kb * 16) ^ ((row & 7) << 4));
  *(s16x8*)dst = o;
}

// ---------------- prep: axT[144][8192] bf16 ---------------------------------
// rows 0..127 = all_x^T, row 128 = ||all_x_k||^2, row 129 = 1.0, 130..143 = 0
__global__ void prep_axT(const float* __restrict__ all_x, u16* __restrict__ axT) {
  __shared__ float tile[64 * 129];
  __shared__ float nallp[256];
  int k0 = blockIdx.x * 64;
  int tid = threadIdx.x;
#pragma unroll
  for (int j = 0; j < 32; ++j) {
    int idx = j * 256 + tid;
    int kk = idx >> 7, d = idx & 127;
    tile[kk * 129 + d] = all_x[(size_t)(k0 + kk) * 128 + d];
  }
  __syncthreads();
  {
    int kk = tid & 63, q = tid >> 6;
    float s = 0.f;
#pragma unroll
    for (int dd = 0; dd < 32; ++dd) { float v = tile[kk * 129 + q * 32 + dd]; s += v * v; }
    nallp[kk * 4 + q] = s;
  }
  {
    int d = tid >> 1, h = tid & 1;
    u16* dst = axT + (size_t)d * 8192 + k0 + h * 32;
#pragma unroll
    for (int c = 0; c < 4; ++c) {
      s16x8 o;
#pragma unroll
      for (int e = 0; e < 8; ++e)
        o[e] = (short)f2bf(tile[(h * 32 + c * 8 + e) * 129 + d]);
      ((s16x8*)dst)[c] = o;
    }
  }
  __syncthreads();
  if (tid < 64) {
    float nv = nallp[tid * 4] + nallp[tid * 4 + 1] + nallp[tid * 4 + 2] + nallp[tid * 4 + 3];
    axT[(size_t)128 * 8192 + k0 + tid] = f2bf(nv);
    axT[(size_t)129 * 8192 + k0 + tid] = 0x3F80;  // 1.0bf
#pragma unroll
    for (int d = 130; d < 144; ++d) axT[(size_t)d * 8192 + k0 + tid] = 0;
  }
}

// ---------------- prep: nsub[i] = ||sub_x_i||^2 ------------------------------
__global__ void prep_nsub(const float* __restrict__ subx, float* __restrict__ nsub) {
  int i = blockIdx.x * 256 + threadIdx.x;   // 4096
  const float* p = subx + (size_t)i * 128;
  float s = 0.f;
#pragma unroll
  for (int c = 0; c < 32; ++c) {
    float4 v = ((const float4*)p)[c];
    s += v.x * v.x + v.y * v.y + v.z * v.z + v.w * v.w;
  }
  nsub[i] = s;
}

// ---------------- contrastive main: online (m,s) over column quarters --------
// grid 512: rb = bid>>2 (64-row block), cq = bid&3 (2048-col quarter)
__global__ __launch_bounds__(256, 2)
void contrast_main(const float* __restrict__ h_i, const float* __restrict__ h_j,
                   const u16* __restrict__ hbf,
                   float* __restrict__ mpart, float* __restrict__ spart,
                   float* __restrict__ pos) {
  __shared__ u16 lds[2][16384];   // 2 x 32KB double buffer
  int bid = blockIdx.x;
  int rb = bid >> 2, cq = bid & 3;
  int tid = threadIdx.x;
  int w = tid >> 6, l = tid & 63, g = l >> 4, l15 = l & 15;
  int r0 = rb * 64 + w * 16;
  int grow = r0 + l15;
  const int C0 = cq * 2048;

  // hoist row fragments (16 rows per wave, K=128) into registers
  s16x8 rf[4];
  {
    const char* rp = (const char*)hbf + (size_t)grow * 256;
    int sw = (grow & 7) << 4;
#pragma unroll
    for (int kk = 0; kk < 4; ++kk)
      rf[kk] = *(const s16x8*)(rp + ((kk * 64 + g * 16) ^ sw));
  }

  float m = -3.0e38f, srun = 0.0f;

  auto stage = [&](int buf, int t) {
    const char* src = (const char*)hbf + (size_t)(C0 + t * 128) * 256 + w * 8192 + (l << 4);
    char* dst = (char*)&lds[buf][0] + w * 8192;
#pragma unroll
    for (int j = 0; j < 8; ++j) gl16(src + j * 1024, dst + j * 1024);
  };

  stage(0, 0);
  __syncthreads();
  int cur = 0;
  for (int t = 0; t < 16; ++t) {
    if (t < 15) stage(cur ^ 1, t + 1);
    const char* base = (const char*)&lds[cur][0];
    int cb0 = C0 + t * 128;
#pragma unroll
    for (int s = 0; s < 8; ++s) {
      int vec = s * 16 + l15;
      const char* vb = base + vec * 256;
      int sw = (vec & 7) << 4;
      f32x4 acc = {0.f, 0.f, 0.f, 0.f};
#pragma unroll
      for (int kk = 0; kk < 4; ++kk) {
        s16x8 a = *(const s16x8*)(vb + ((kk * 64 + g * 16) ^ sw));
        acc = mfma16(a, rf[kk], acc);
      }
      float v0 = acc[0], v1 = acc[1], v2 = acc[2], v3 = acc[3];
      int cb = cb0 + s * 16;
      if (cb == r0) {                 // diagonal subtile (wave-uniform, hits once)
        int dc = l15 - g * 4;
        v0 = (dc == 0) ? -3.0e38f : v0;
        v1 = (dc == 1) ? -3.0e38f : v1;
        v2 = (dc == 2) ? -3.0e38f : v2;
        v3 = (dc == 3) ? -3.0e38f : v3;
      }
      float tmax = fmaxf(fmaxf(v0, v1), fmaxf(v2, v3));
      float nm = fmaxf(m, tmax);
      float e = fexp2(v0 - nm) + fexp2(v1 - nm) + fexp2(v2 - nm) + fexp2(v3 - nm);
      srun = fmaf(srun, fexp2(m - nm), e);
      m = nm;
    }
    __syncthreads();
    cur ^= 1;
  }

  // combine the 4 lane-groups holding the same sim-row (lanes xor 16, 32)
#pragma unroll
  for (int d = 16; d <= 32; d <<= 1) {
    float om = __shfl_xor(m, d, 64);
    float os = __shfl_xor(srun, d, 64);
    float nm = fmaxf(m, om);
    srun = srun * fexp2(m - nm) + os * fexp2(om - nm);
    m = nm;
  }
  if (l < 16) {
    mpart[cq * 8192 + grow] = m;
    spart[cq * 8192 + grow] = srun;
  }
  if (cq == 0) {   // fp32-exact positives: pos_i = 2*dot(h_i[r], h_j[r])
    int r = grow & 4095;
    const float* pa = h_i + (size_t)r * 128;
    const float* pb = h_j + (size_t)r * 128;
    float dp = 0.f;
#pragma unroll
    for (int c = 0; c < 8; ++c) {
      float4 a4 = *(const float4*)(pa + g * 32 + c * 4);
      float4 b4 = *(const float4*)(pb + g * 32 + c * 4);
      dp += a4.x * b4.x + a4.y * b4.y + a4.z * b4.z + a4.w * b4.w;
    }
    dp += __shfl_xor(dp, 16, 64);
    dp += __shfl_xor(dp, 32, 64);
    if (l < 16) pos[grow] = 2.0f * dp;
  }
}

// ---------------- contrastive combine: merge quarters, lse - pos -------------
__global__ void contrast_combine(const float* __restrict__ mpart, const float* __restrict__ spart,
                                 const float* __restrict__ pos, float* __restrict__ cpart) {
  int row = blockIdx.x * 256 + threadIdx.x;   // 8192
  float m0 = mpart[row], m1 = mpart[8192 + row], m2 = mpart[16384 + row], m3 = mpart[24576 + row];
  float M = fmaxf(fmaxf(m0, m1), fmaxf(m2, m3));
  float S = spart[row] * fexp2(m0 - M) + spart[8192 + row] * fexp2(m1 - M) +
            spart[16384 + row] * fexp2(m2 - M) + spart[24576 + row] * fexp2(m3 - M);
  float c = LN2F * (M + flog2(S)) - pos[row];
#pragma unroll
  for (int d = 1; d < 64; d <<= 1) c += __shfl_xor(c, d, 64);
  __shared__ float wsum[4];
  int l = threadIdx.x & 63, w = threadIdx.x >> 6;
  if (l == 0) wsum[w] = c;
  __syncthreads();
  if (threadIdx.x == 0) cpart[blockIdx.x] = wsum[0] + wsum[1] + wsum[2] + wsum[3];
}

// ---------------- graph: one pass over G, fused t1+t2-2*t3 -------------------
// grid 1024: rt = bid>>2 (16 G-rows), kq = bid&3; wave w owns k in [kq*2048+w*512, +512)
__global__ __launch_bounds__(256, 4)
void graph_main(const float* __restrict__ G, const float* __restrict__ subx,
                const u16* __restrict__ axT, const float* __restrict__ nsub,
                float* __restrict__ gpart) {
  int bid = blockIdx.x;
  int rt = bid >> 2, kq = bid & 3;
  int tid = threadIdx.x, w = tid >> 6, l = tid & 63, g = l >> 4, l15 = l & 15;
  int i = rt * 16 + l15;
  size_t kbase = (size_t)kq * 2048 + (size_t)w * 512;
  const float* gp = G + (size_t)i * 8192 + kbase + g * 8;
  const u16* ap = axT + (size_t)l15 * 8192 + kbase + g * 8;
  f32x4 acc[9];
#pragma unroll
  for (int t = 0; t < 9; ++t) acc[t] = (f32x4){0.f, 0.f, 0.f, 0.f};
  for (int ks = 0; ks < 16; ++ks) {
    float4 ga = *(const float4*)(gp);
    float4 gb = *(const float4*)(gp + 4);
    gp += 32;
    s16x8 bf;
    bf[0] = (short)f2bf(ga.x); bf[1] = (short)f2bf(ga.y);
    bf[2] = (short)f2bf(ga.z); bf[3] = (short)f2bf(ga.w);
    bf[4] = (short)f2bf(gb.x); bf[5] = (short)f2bf(gb.y);
    bf[6] = (short)f2bf(gb.z); bf[7] = (short)f2bf(gb.w);
    const u16* a = ap + ks * 32;
#pragma unroll
    for (int t = 0; t < 9; ++t) {
      s16x8 af = *(const s16x8*)(a + (size_t)t * 16 * 8192);
      acc[t] = mfma16(af, bf, acc[t]);
    }
  }
  // epilogue: lane holds y[i][d], d = t*16 + g*4 + reg
  float p = 0.f;
#pragma unroll
  for (int t = 0; t < 8; ++t) {
    float4 sx = *(const float4*)(subx + (size_t)i * 128 + t * 16 + g * 4);
    p -= 2.0f * (acc[t][0] * sx.x + acc[t][1] * sx.y + acc[t][2] * sx.z + acc[t][3] * sx.w);
  }
  if (g == 0) p += acc[8][0] + acc[8][1] * nsub[i];   // d=128 -> t2, d=129 -> r_i*nsub_i
#pragma unroll
  for (int d = 1; d < 64; d <<= 1) p += __shfl_xor(p, d, 64);
  __shared__ float wsum[4];
  if (l == 0) wsum[w] = p;
  __syncthreads();
  if (tid == 0) gpart[bid] = wsum[0] + wsum[1] + wsum[2] + wsum[3];
}

// ---------------- final: deterministic scalar reduction ----------------------
__global__ void final_sum(const float* __restrict__ cpart, const float* __restrict__ gpart,
                          float* __restrict__ out) {
  int tid = threadIdx.x;
  double a = 0.0;
  for (int idx = tid; idx < 1024; idx += 256) a += (double)gpart[idx];
  double c = (tid < 32) ? (double)cpart[tid] : 0.0;
#pragma unroll
  for (int d = 1; d < 64; d <<= 1) {
    a += __shfl_xor(a, d, 64);
    c += __shfl_xor(c, d, 64);
  }
  __shared__ double wa[4], wc[4];
  int l = tid & 63, w = tid >> 6;
  if (l == 0) { wa[w] = a; wc[w] = c; }
  __syncthreads();
  if (tid == 0) {
    double gsum = wa[0] + wa[1] + wa[2] + wa[3];
    double csum = wc[0] + wc[1] + wc[2] + wc[3];
    out[0] = (float)(csum / 8192.0 + gsum / (4096.0 * 8192.0));
  }
}

extern "C" void kernel_launch(void* const* d_in, const int* in_sizes, int n_in,
                              void* d_out, int out_size, void* d_ws, size_t ws_size,
                              hipStream_t stream) {
  const float* h_i = (const float*)d_in[0];
  const float* h_j = (const float*)d_in[1];
  const float* G   = (const float*)d_in[2];
  const float* sx  = (const float*)d_in[3];
  const float* ax  = (const float*)d_in[4];
  char* ws = (char*)d_ws;
  u16*   hbf   = (u16*)(ws);                    // 2,097,152 B
  u16*   axT   = (u16*)(ws + 2097152);          // 2,359,296 B
  float* nsub  = (float*)(ws + 4456448);        // 16,384 B
  float* mpart = (float*)(ws + 4472832);        // 131,072 B
  float* spart = (float*)(ws + 4603904);        // 131,072 B
  float* pos   = (float*)(ws + 4734976);        // 32,768 B
  float* cpart = (float*)(ws + 4767744);        // 128 B
  float* gpart = (float*)(ws + 4767872);        // 4,096 B
  float* out = (float*)d_out;

  prep_h<<<dim3(512), dim3(256), 0, stream>>>(h_i, h_j, hbf);
  prep_axT<<<dim3(128), dim3(256), 0, stream>>>(ax, axT);
  prep_nsub<<<dim3(16), dim3(256), 0, stream>>>(sx, nsub);
  contrast_main<<<dim3(512), dim3(256), 0, stream>>>(h_i, h_j, hbf, mpart, spart, pos);
  graph_main<<<dim3(1024), dim3(256), 0, stream>>>(G, sx, axT, nsub, gpart);
  contrast_combine<<<dim3(32), dim3(256), 0, stream>>>(mpart, spart, pos, cpart);
  final_sum<<<dim3(1), dim3(256), 0, stream>>>(cpart, gpart, out);
}

// Round 2
// 89.782 us; speedup vs baseline: 1.5501x; 1.5501x over previous
//
#include <hip/hip_runtime.h>
#include <hip/hip_bf16.h>

typedef __attribute__((ext_vector_type(4))) float f32x4;
typedef __attribute__((ext_vector_type(8))) short s16x8;
typedef unsigned short u16;
typedef unsigned int u32;

#define ALPHA 1.6986436f          /* sqrt(2*log2(e)) : sim*log2e = dot(a*h, a*h) */
#define LN2F  0.69314718056f

__device__ __forceinline__ u16 f2bf(float x) {
  union { float f; u32 u; } v; v.f = x;
  u32 r = v.u + 0x7fffu + ((v.u >> 16) & 1u);
  return (u16)(r >> 16);
}

#if __has_builtin(__builtin_amdgcn_exp2f)
__device__ __forceinline__ float fexp2(float x) { return __builtin_amdgcn_exp2f(x); }
#else
__device__ __forceinline__ float fexp2(float x) { return exp2f(x); }
#endif
#if __has_builtin(__builtin_amdgcn_logf)
__device__ __forceinline__ float flog2(float x) { return __builtin_amdgcn_logf(x); }
#else
__device__ __forceinline__ float flog2(float x) { return log2f(x); }
#endif

__device__ __forceinline__ f32x4 mfma16(s16x8 a, s16x8 b, f32x4 c) {
  return __builtin_amdgcn_mfma_f32_16x16x32_bf16(a, b, c, 0, 0, 0);
}

__device__ __forceinline__ void gl16(const void* g, void* l) {
  __builtin_amdgcn_global_load_lds(
      (const __attribute__((address_space(1))) u32*)g,
      (__attribute__((address_space(3))) u32*)l, 16, 0, 0);
}

// ---------------- prep: h -> bf16, scaled by ALPHA, swizzled layout ----------
__global__ void prep_h(const float* __restrict__ h_i, const float* __restrict__ h_j,
                       u16* __restrict__ hbf) {
  int t = blockIdx.x * 256 + threadIdx.x;       // 131072 threads
  int row = t >> 4, kb = t & 15;
  const float* src = (row < 4096 ? h_i + (size_t)row * 128
                                 : h_j + (size_t)(row - 4096) * 128) + kb * 8;
  float4 f0 = *(const float4*)(src);
  float4 f1 = *(const float4*)(src + 4);
  s16x8 o;
  o[0] = (short)f2bf(ALPHA * f0.x); o[1] = (short)f2bf(ALPHA * f0.y);
  o[2] = (short)f2bf(ALPHA * f0.z); o[3] = (short)f2bf(ALPHA * f0.w);
  o[4] = (short)f2bf(ALPHA * f1.x); o[5] = (short)f2bf(ALPHA * f1.y);
  o[6] = (short)f2bf(ALPHA * f1.z); o[7] = (short)f2bf(ALPHA * f1.w);
  char* dst = (char*)hbf + (size_t)row * 256 + ((kb * 16) ^ ((row & 7) << 4));
  *(s16x8*)dst = o;
}

// ---------------- prep: axTs tiles + nall ------------------------------------
// axTs[kt64][r][128B]: row r = all_x[:,d=r] for k in [kt64*64, +64), bf16,
// byte swizzle within row: chunk kb at (kb*16) ^ ((r&7)<<4). nall[k] = ||all_x_k||^2.
__global__ void prep_axT(const float* __restrict__ all_x, u16* __restrict__ axTs,
                         float* __restrict__ nall) {
  __shared__ float tile[64 * 132];
  int kt = blockIdx.x, tid = threadIdx.x;
  for (int hk = 0; hk < 2; ++hk) {
    int k0 = kt * 128 + hk * 64;
#pragma unroll
    for (int j = 0; j < 8; ++j) {
      int idx = (j * 256 + tid) * 4;
      int kk = idx >> 7, d = idx & 127;
      *(float4*)&tile[kk * 132 + d] = *(const float4*)&all_x[(size_t)(k0 + kk) * 128 + d];
    }
    __syncthreads();
    {
      int kk = tid >> 2, q = tid & 3;
      float s = 0.f;
#pragma unroll
      for (int dd = 0; dd < 32; ++dd) { float v = tile[kk * 132 + q * 32 + dd]; s += v * v; }
      s += __shfl_xor(s, 1, 64);
      s += __shfl_xor(s, 2, 64);
      if (q == 0) nall[k0 + kk] = s;
    }
    int kt64 = kt * 2 + hk;
#pragma unroll
    for (int j = 0; j < 4; ++j) {
      int c = j * 256 + tid;
      int r = c & 127, cb = c >> 7;   // cb in [j*2, j*2+2)
      s16x8 o;
#pragma unroll
      for (int e = 0; e < 8; ++e) o[e] = (short)f2bf(tile[(cb * 8 + e) * 132 + r]);
      *(s16x8*)((char*)axTs + (size_t)kt64 * 16384 + r * 128 + ((cb * 16) ^ ((r & 7) << 4))) = o;
    }
    __syncthreads();
  }
}

// ---------------- prep: nsub[i] = ||sub_x_i||^2 ------------------------------
__global__ void prep_nsub(const float* __restrict__ subx, float* __restrict__ nsub) {
  int i = blockIdx.x * 256 + threadIdx.x;   // 4096
  const float* p = subx + (size_t)i * 128;
  float s = 0.f;
#pragma unroll
  for (int c = 0; c < 32; ++c) {
    float4 v = ((const float4*)p)[c];
    s += v.x * v.x + v.y * v.y + v.z * v.z + v.w * v.w;
  }
  nsub[i] = s;
}

// ---------------- contrastive main: online (m,s) over column quarters --------
__global__ __launch_bounds__(256, 2)
void contrast_main(const float* __restrict__ h_i, const float* __restrict__ h_j,
                   const u16* __restrict__ hbf,
                   float* __restrict__ mpart, float* __restrict__ spart,
                   float* __restrict__ pos) {
  __shared__ u16 lds[2][16384];   // 2 x 32KB double buffer
  int bid = blockIdx.x;
  int rb = bid >> 2, cq = bid & 3;
  int tid = threadIdx.x;
  int w = tid >> 6, l = tid & 63, g = l >> 4, l15 = l & 15;
  int r0 = rb * 64 + w * 16;
  int grow = r0 + l15;
  const int C0 = cq * 2048;

  s16x8 rf[4];
  {
    const char* rp = (const char*)hbf + (size_t)grow * 256;
    int sw = (grow & 7) << 4;
#pragma unroll
    for (int kk = 0; kk < 4; ++kk)
      rf[kk] = *(const s16x8*)(rp + ((kk * 64 + g * 16) ^ sw));
  }

  float m = -3.0e38f, srun = 0.0f;

  auto stage = [&](int buf, int t) {
    const char* src = (const char*)hbf + (size_t)(C0 + t * 128) * 256 + w * 8192 + (l << 4);
    char* dst = (char*)&lds[buf][0] + w * 8192;
#pragma unroll
    for (int j = 0; j < 8; ++j) gl16(src + j * 1024, dst + j * 1024);
  };

  stage(0, 0);
  __syncthreads();
  int cur = 0;
  for (int t = 0; t < 16; ++t) {
    if (t < 15) stage(cur ^ 1, t + 1);
    const char* base = (const char*)&lds[cur][0];
    int cb0 = C0 + t * 128;
#pragma unroll
    for (int s = 0; s < 8; ++s) {
      int vec = s * 16 + l15;
      const char* vb = base + vec * 256;
      int sw = (vec & 7) << 4;
      f32x4 acc = {0.f, 0.f, 0.f, 0.f};
#pragma unroll
      for (int kk = 0; kk < 4; ++kk) {
        s16x8 a = *(const s16x8*)(vb + ((kk * 64 + g * 16) ^ sw));
        acc = mfma16(a, rf[kk], acc);
      }
      float v0 = acc[0], v1 = acc[1], v2 = acc[2], v3 = acc[3];
      int cb = cb0 + s * 16;
      if (cb == r0) {                 // diagonal subtile (wave-uniform, hits once)
        int dc = l15 - g * 4;
        v0 = (dc == 0) ? -3.0e38f : v0;
        v1 = (dc == 1) ? -3.0e38f : v1;
        v2 = (dc == 2) ? -3.0e38f : v2;
        v3 = (dc == 3) ? -3.0e38f : v3;
      }
      float tmax = fmaxf(fmaxf(v0, v1), fmaxf(v2, v3));
      float nm = fmaxf(m, tmax);
      float e = fexp2(v0 - nm) + fexp2(v1 - nm) + fexp2(v2 - nm) + fexp2(v3 - nm);
      srun = fmaf(srun, fexp2(m - nm), e);
      m = nm;
    }
    __syncthreads();
    cur ^= 1;
  }

#pragma unroll
  for (int d = 16; d <= 32; d <<= 1) {
    float om = __shfl_xor(m, d, 64);
    float os = __shfl_xor(srun, d, 64);
    float nm = fmaxf(m, om);
    srun = srun * fexp2(m - nm) + os * fexp2(om - nm);
    m = nm;
  }
  if (l < 16) {
    mpart[cq * 8192 + grow] = m;
    spart[cq * 8192 + grow] = srun;
  }
  if (cq == 0) {   // fp32-exact positives
    int r = grow & 4095;
    const float* pa = h_i + (size_t)r * 128;
    const float* pb = h_j + (size_t)r * 128;
    float dp = 0.f;
#pragma unroll
    for (int c = 0; c < 8; ++c) {
      float4 a4 = *(const float4*)(pa + g * 32 + c * 4);
      float4 b4 = *(const float4*)(pb + g * 32 + c * 4);
      dp += a4.x * b4.x + a4.y * b4.y + a4.z * b4.z + a4.w * b4.w;
    }
    dp += __shfl_xor(dp, 16, 64);
    dp += __shfl_xor(dp, 32, 64);
    if (l < 16) pos[grow] = 2.0f * dp;
  }
}

// ---------------- contrastive combine ----------------------------------------
__global__ void contrast_combine(const float* __restrict__ mpart, const float* __restrict__ spart,
                                 const float* __restrict__ pos, float* __restrict__ cpart) {
  int row = blockIdx.x * 256 + threadIdx.x;   // 8192
  float m0 = mpart[row], m1 = mpart[8192 + row], m2 = mpart[16384 + row], m3 = mpart[24576 + row];
  float M = fmaxf(fmaxf(m0, m1), fmaxf(m2, m3));
  float S = spart[row] * fexp2(m0 - M) + spart[8192 + row] * fexp2(m1 - M) +
            spart[16384 + row] * fexp2(m2 - M) + spart[24576 + row] * fexp2(m3 - M);
  float c = LN2F * (M + flog2(S)) - pos[row];
#pragma unroll
  for (int d = 1; d < 64; d <<= 1) c += __shfl_xor(c, d, 64);
  __shared__ float wsum[4];
  int l = threadIdx.x & 63, w = threadIdx.x >> 6;
  if (l == 0) wsum[w] = c;
  __syncthreads();
  if (threadIdx.x == 0) cpart[blockIdx.x] = wsum[0] + wsum[1] + wsum[2] + wsum[3];
}

// ---------------- graph: LDS-staged GEMM, one pass over G --------------------
// grid 512: mt = bid>>4 (128 G-rows), kq = bid&15 (512 k's). 512 thr = 8 waves,
// wave w owns rows mt*128 + w*16 .. +16, all 128 N, k-range kq*512..+512.
__global__ __launch_bounds__(512, 4)
void graph_main(const float* __restrict__ G, const float* __restrict__ subx,
                const u16* __restrict__ axTs, const float* __restrict__ nall,
                const float* __restrict__ nsub, float* __restrict__ gpart) {
  __shared__ char lds[2][16384];    // double-buffered 64-k axT tile
  __shared__ float nll[512];
  __shared__ float wsum[8];
  int bid = blockIdx.x;
  int mt = bid >> 4, kq = bid & 15;
  int tid = threadIdx.x, w = tid >> 6, l = tid & 63, g = l >> 4, l15 = l & 15;
  int i = mt * 128 + w * 16 + l15;
  int kw = kq * 512;
  const float* gbase = G + (size_t)i * 8192 + kw;
  float nsub_i = nsub[i];

  if (tid < 128) *(float4*)&nll[tid * 4] = *(const float4*)&nall[kw + tid * 4];

  auto stage = [&](int buf, int t) {
    const char* src = (const char*)axTs + ((size_t)(kq * 8 + t)) * 16384 + w * 1024 + (l << 4);
    char* dst = &lds[buf][0] + w * 1024;
    gl16(src, dst);
    gl16(src + 8192, dst + 8192);
  };

  f32x4 acc[8];
#pragma unroll
  for (int t16 = 0; t16 < 8; ++t16) acc[t16] = (f32x4){0.f, 0.f, 0.f, 0.f};
  float rsum = 0.f, nsum = 0.f;

  stage(0, 0);
  __syncthreads();
  int cur = 0;
  for (int t = 0; t < 8; ++t) {
    if (t < 7) stage(cur ^ 1, t + 1);
    const char* base = &lds[cur][0];
    const float* gp = gbase + t * 64 + g * 8;
#pragma unroll
    for (int ks = 0; ks < 2; ++ks) {
      float4 ga = *(const float4*)(gp + ks * 32);
      float4 gb = *(const float4*)(gp + ks * 32 + 4);
      float4 na = *(const float4*)&nll[t * 64 + ks * 32 + g * 8];
      float4 nb = *(const float4*)&nll[t * 64 + ks * 32 + g * 8 + 4];
      rsum += (ga.x + ga.y + ga.z + ga.w) + (gb.x + gb.y + gb.z + gb.w);
      nsum += ga.x * na.x + ga.y * na.y + ga.z * na.z + ga.w * na.w
            + gb.x * nb.x + gb.y * nb.y + gb.z * nb.z + gb.w * nb.w;
      s16x8 bf;
      bf[0] = (short)f2bf(ga.x); bf[1] = (short)f2bf(ga.y);
      bf[2] = (short)f2bf(ga.z); bf[3] = (short)f2bf(ga.w);
      bf[4] = (short)f2bf(gb.x); bf[5] = (short)f2bf(gb.y);
      bf[6] = (short)f2bf(gb.z); bf[7] = (short)f2bf(gb.w);
#pragma unroll
      for (int t16 = 0; t16 < 8; ++t16) {
        int row = t16 * 16 + l15;
        s16x8 af = *(const s16x8*)(base + row * 128 + ((ks * 64 + g * 16) ^ ((row & 7) << 4)));
        acc[t16] = mfma16(af, bf, acc[t16]);
      }
    }
    __syncthreads();
    cur ^= 1;
  }

  // epilogue: lane (g,l15) holds y[i][d], d = t16*16 + g*4 + reg
  float p = nsum + rsum * nsub_i;
#pragma unroll
  for (int t16 = 0; t16 < 8; ++t16) {
    float4 sx = *(const float4*)(subx + (size_t)i * 128 + t16 * 16 + g * 4);
    p -= 2.0f * (acc[t16][0] * sx.x + acc[t16][1] * sx.y + acc[t16][2] * sx.z + acc[t16][3] * sx.w);
  }
#pragma unroll
  for (int d = 1; d < 64; d <<= 1) p += __shfl_xor(p, d, 64);
  if (l == 0) wsum[w] = p;
  __syncthreads();
  if (tid == 0) {
    float s = 0.f;
#pragma unroll
    for (int q = 0; q < 8; ++q) s += wsum[q];
    gpart[bid] = s;
  }
}

// ---------------- final: deterministic scalar reduction ----------------------
__global__ void final_sum(const float* __restrict__ cpart, const float* __restrict__ gpart,
                          float* __restrict__ out) {
  int tid = threadIdx.x;
  double a = 0.0;
  for (int idx = tid; idx < 512; idx += 256) a += (double)gpart[idx];
  double c = (tid < 32) ? (double)cpart[tid] : 0.0;
#pragma unroll
  for (int d = 1; d < 64; d <<= 1) {
    a += __shfl_xor(a, d, 64);
    c += __shfl_xor(c, d, 64);
  }
  __shared__ double wa[4], wc[4];
  int l = tid & 63, w = tid >> 6;
  if (l == 0) { wa[w] = a; wc[w] = c; }
  __syncthreads();
  if (tid == 0) {
    double gsum = wa[0] + wa[1] + wa[2] + wa[3];
    double csum = wc[0] + wc[1] + wc[2] + wc[3];
    out[0] = (float)(csum / 8192.0 + gsum / (4096.0 * 8192.0));
  }
}

extern "C" void kernel_launch(void* const* d_in, const int* in_sizes, int n_in,
                              void* d_out, int out_size, void* d_ws, size_t ws_size,
                              hipStream_t stream) {
  const float* h_i = (const float*)d_in[0];
  const float* h_j = (const float*)d_in[1];
  const float* G   = (const float*)d_in[2];
  const float* sx  = (const float*)d_in[3];
  const float* ax  = (const float*)d_in[4];
  char* ws = (char*)d_ws;
  u16*   hbf   = (u16*)(ws);                    // 2,097,152 B
  u16*   axTs  = (u16*)(ws + 2097152);          // 2,097,152 B (128 tiles x 16KB)
  float* nall  = (float*)(ws + 4194304);        // 32,768 B
  float* nsub  = (float*)(ws + 4227072);        // 16,384 B
  float* mpart = (float*)(ws + 4243456);        // 131,072 B
  float* spart = (float*)(ws + 4374528);        // 131,072 B
  float* pos   = (float*)(ws + 4505600);        // 32,768 B
  float* cpart = (float*)(ws + 4538368);        // 128 B
  float* gpart = (float*)(ws + 4538496);        // 2,048 B
  float* out = (float*)d_out;

  prep_h<<<dim3(512), dim3(256), 0, stream>>>(h_i, h_j, hbf);
  prep_axT<<<dim3(64), dim3(256), 0, stream>>>(ax, axTs, nall);
  prep_nsub<<<dim3(16), dim3(256), 0, stream>>>(sx, nsub);
  contrast_main<<<dim3(512), dim3(256), 0, stream>>>(h_i, h_j, hbf, mpart, spart, pos);
  graph_main<<<dim3(512), dim3(512), 0, stream>>>(G, sx, axTs, nall, nsub, gpart);
  contrast_combine<<<dim3(32), dim3(256), 0, stream>>>(mpart, spart, pos, cpart);
  final_sum<<<dim3(1), dim3(256), 0, stream>>>(cpart, gpart, out);
}

// Round 3
// 74.830 us; speedup vs baseline: 1.8598x; 1.1998x over previous
//
#include <hip/hip_runtime.h>
#include <hip/hip_bf16.h>

typedef __attribute__((ext_vector_type(4)))  float f32x4;
typedef __attribute__((ext_vector_type(16))) float f32x16;
typedef __attribute__((ext_vector_type(8)))  short s16x8;
typedef unsigned short u16;
typedef unsigned int u32;

#define ALPHA 1.6986436f          /* sqrt(2*log2(e)) : dot(a*h, a*h) = sim*log2e */
#define LN2F  0.69314718056f
#define COFF  128.0f              /* static log2-domain offset for softmax */

__device__ __forceinline__ u16 f2bf(float x) {
  union { float f; u32 u; } v; v.f = x;
  u32 r = v.u + 0x7fffu + ((v.u >> 16) & 1u);
  return (u16)(r >> 16);
}

#if __has_builtin(__builtin_amdgcn_exp2f)
__device__ __forceinline__ float fexp2(float x) { return __builtin_amdgcn_exp2f(x); }
#else
__device__ __forceinline__ float fexp2(float x) { return exp2f(x); }
#endif
#if __has_builtin(__builtin_amdgcn_logf)
__device__ __forceinline__ float flog2(float x) { return __builtin_amdgcn_logf(x); }
#else
__device__ __forceinline__ float flog2(float x) { return log2f(x); }
#endif

__device__ __forceinline__ f32x16 mfma32(s16x8 a, s16x8 b, f32x16 c) {
  return __builtin_amdgcn_mfma_f32_32x32x16_bf16(a, b, c, 0, 0, 0);
}
__device__ __forceinline__ f32x16 zero16() {
  f32x16 z;
#pragma unroll
  for (int i = 0; i < 16; ++i) z[i] = 0.f;
  return z;
}
__device__ __forceinline__ void gl16(const void* g, void* l) {
  __builtin_amdgcn_global_load_lds(
      (const __attribute__((address_space(1))) u32*)g,
      (__attribute__((address_space(3))) u32*)l, 16, 0, 0);
}

// =================== prep (fused): hbf + pos4 | axG/axN | nsub ===============
// hbf row r: byte off = r*256 + ((2k) ^ ((r&7)<<4)), bf16 scaled by ALPHA.
// axG[kc][d][32B]: bf16(all_x[kc*16+kk][d]) at byte kc*4096 + d*32 + kk*2.
// axN[kc][row][32B]: row0 = bf16(nall[kc*16+kk]), row1 = 1.0, rows 2..31 = 0.
__global__ __launch_bounds__(256)
void prep_all(const float* __restrict__ h_i, const float* __restrict__ h_j,
              const float* __restrict__ all_x, const float* __restrict__ subx,
              u16* __restrict__ hbf, u16* __restrict__ axG, u16* __restrict__ axN,
              float* __restrict__ nsub, float* __restrict__ pos4) {
  __shared__ float tile[64 * 132];
  __shared__ float nals[64];
  int bid = blockIdx.x, tid = threadIdx.x;
  if (bid < 512) {
    // ---- hbf + pos4 ----
    int t = bid * 256 + tid;
    int row = t >> 4, kb = t & 15;
    const float* src = (row < 4096 ? h_i + (size_t)row * 128
                                   : h_j + (size_t)(row - 4096) * 128) + kb * 8;
    float4 f0 = *(const float4*)(src);
    float4 f1 = *(const float4*)(src + 4);
    s16x8 o;
    o[0] = (short)f2bf(ALPHA * f0.x); o[1] = (short)f2bf(ALPHA * f0.y);
    o[2] = (short)f2bf(ALPHA * f0.z); o[3] = (short)f2bf(ALPHA * f0.w);
    o[4] = (short)f2bf(ALPHA * f1.x); o[5] = (short)f2bf(ALPHA * f1.y);
    o[6] = (short)f2bf(ALPHA * f1.z); o[7] = (short)f2bf(ALPHA * f1.w);
    char* dst = (char*)hbf + (size_t)row * 256 + ((kb * 16) ^ ((row & 7) << 4));
    *(s16x8*)dst = o;
    if (row < 4096) {   // fp32-exact positives, reduced over the 16-thread row group
      const float* srcj = h_j + (size_t)row * 128 + kb * 8;
      float4 g0 = *(const float4*)(srcj);
      float4 g1 = *(const float4*)(srcj + 4);
      float dp = f0.x * g0.x + f0.y * g0.y + f0.z * g0.z + f0.w * g0.w
               + f1.x * g1.x + f1.y * g1.y + f1.z * g1.z + f1.w * g1.w;
      dp += __shfl_xor(dp, 1, 64);
      dp += __shfl_xor(dp, 2, 64);
      dp += __shfl_xor(dp, 4, 64);
      dp += __shfl_xor(dp, 8, 64);
      if ((tid & 15) == 0) pos4[row] = 2.0f * dp;
    }
  } else if (bid < 640) {
    // ---- axG + axN (64 k rows of all_x per block) ----
    int ab = bid - 512;           // 0..127
    int k0 = ab * 64;
#pragma unroll
    for (int j = 0; j < 8; ++j) {
      int idx = (j * 256 + tid) * 4;
      int kk = idx >> 7, d = idx & 127;
      *(float4*)&tile[kk * 132 + d] = *(const float4*)&all_x[(size_t)(k0 + kk) * 128 + d];
    }
    __syncthreads();
    {
      int kk = tid >> 2, q = tid & 3;
      float s = 0.f;
#pragma unroll
      for (int dd = 0; dd < 32; ++dd) { float v = tile[kk * 132 + q * 32 + dd]; s += v * v; }
      s += __shfl_xor(s, 1, 64);
      s += __shfl_xor(s, 2, 64);
      if (q == 0) nals[kk] = s;
    }
    __syncthreads();
#pragma unroll
    for (int half = 0; half < 2; ++half) {
      int tgt = half * 256 + tid;
      int f = tgt >> 7, d = tgt & 127;    // kc-local f in 0..3
      int kc = ab * 4 + f;
      u16* dp = axG + (size_t)kc * 2048 + d * 16;
      s16x8 o0, o1;
#pragma unroll
      for (int kk = 0; kk < 8; ++kk) {
        o0[kk] = (short)f2bf(tile[(f * 16 + kk) * 132 + d]);
        o1[kk] = (short)f2bf(tile[(f * 16 + 8 + kk) * 132 + d]);
      }
      ((s16x8*)dp)[0] = o0; ((s16x8*)dp)[1] = o1;
    }
    if (tid < 128) {
      int f = tid >> 5, row = tid & 31;
      int kc = ab * 4 + f;
      u16* dp = axN + (size_t)kc * 512 + row * 16;
      s16x8 o0, o1;
#pragma unroll
      for (int kk = 0; kk < 8; ++kk) {
        u16 v0 = 0, v1 = 0;
        if (row == 0) { v0 = f2bf(nals[f * 16 + kk]); v1 = f2bf(nals[f * 16 + 8 + kk]); }
        else if (row == 1) { v0 = 0x3F80; v1 = 0x3F80; }
        o0[kk] = (short)v0; o1[kk] = (short)v1;
      }
      ((s16x8*)dp)[0] = o0; ((s16x8*)dp)[1] = o1;
    }
  } else {
    // ---- nsub ----
    int i = (bid - 640) * 256 + tid;
    const float* p = subx + (size_t)i * 128;
    float s = 0.f;
#pragma unroll
    for (int c = 0; c < 32; ++c) {
      float4 v = ((const float4*)p)[c];
      s += v.x * v.x + v.y * v.y + v.z * v.z + v.w * v.w;
    }
    nsub[i] = s;
  }
}

// =================== main (fused): graph + contrast ==========================
// bid%3 < 2 -> graph block (1024 total): gid=(bid/3)*2+(bid%3); mt=gid>>5, kq=gid&31
//   4 waves x 32 G-rows = 128 rows, k-range kq*256..+256; no barriers in k-loop.
// bid%3 == 2 -> contrast block (512): cid=bid/3; rt=cid>>3 (128 rows), oct=cid&7
//   (1024 cols); static-offset softmax, LDS-staged col tiles.
__global__ __launch_bounds__(256, 4)
void main_fused(const float* __restrict__ G, const float* __restrict__ subx,
                const u16* __restrict__ axG, const u16* __restrict__ axN,
                const float* __restrict__ nsub, const u16* __restrict__ hbf,
                float* __restrict__ spart, float* __restrict__ gpart) {
  __shared__ u16 lds[2][8192];
  __shared__ float wsum[4];
  int bid = blockIdx.x, tid = threadIdx.x;
  int lane = tid & 63, w = tid >> 6, il = lane & 31, hi = lane >> 5;
  int base = bid / 3, q = bid - base * 3;

  if (q < 2) {
    // ------------------ graph ------------------
    int gid = base * 2 + q;
    int mt = gid >> 5, kq = gid & 31;
    int i = mt * 128 + w * 32 + il;
    const float* gb = G + (size_t)i * 8192 + kq * 256;
    f32x16 acc0 = zero16(), acc1 = zero16(), acc2 = zero16(), acc3 = zero16(), accN = zero16();
#pragma unroll 1
    for (int t = 0; t < 4; ++t) {
      int ko = t * 64;
      s16x8 bfr[4];
#pragma unroll
      for (int f = 0; f < 4; ++f) {
        const float* gp = gb + ko + f * 16 + hi * 8;
        float4 ga = *(const float4*)(gp);
        float4 gc = *(const float4*)(gp + 4);
        s16x8 bb;
        bb[0] = (short)f2bf(ga.x); bb[1] = (short)f2bf(ga.y);
        bb[2] = (short)f2bf(ga.z); bb[3] = (short)f2bf(ga.w);
        bb[4] = (short)f2bf(gc.x); bb[5] = (short)f2bf(gc.y);
        bb[6] = (short)f2bf(gc.z); bb[7] = (short)f2bf(gc.w);
        bfr[f] = bb;
      }
      int kc0 = kq * 16 + t * 4;
#pragma unroll
      for (int f = 0; f < 4; ++f) {
        const char* ab = (const char*)axG + (size_t)(kc0 + f) * 4096 + il * 32 + hi * 16;
        s16x8 a0 = *(const s16x8*)(ab);
        s16x8 a1 = *(const s16x8*)(ab + 1024);
        s16x8 a2 = *(const s16x8*)(ab + 2048);
        s16x8 a3 = *(const s16x8*)(ab + 3072);
        s16x8 an = *(const s16x8*)((const char*)axN + (size_t)(kc0 + f) * 1024 + il * 32 + hi * 16);
        acc0 = mfma32(a0, bfr[f], acc0);
        acc1 = mfma32(a1, bfr[f], acc1);
        acc2 = mfma32(a2, bfr[f], acc2);
        acc3 = mfma32(a3, bfr[f], acc3);
        accN = mfma32(an, bfr[f], accN);
      }
    }
    // epilogue: acc{t32}[r] = y[i][d], d = t32*32 + (r&3) + 8*(r>>2) + 4*hi
    float p = 0.f;
    const float* sxr = subx + (size_t)i * 128;
#pragma unroll
    for (int rq = 0; rq < 4; ++rq) {
      float4 s0 = *(const float4*)(sxr + 0 * 32 + rq * 8 + hi * 4);
      float4 s1 = *(const float4*)(sxr + 1 * 32 + rq * 8 + hi * 4);
      float4 s2 = *(const float4*)(sxr + 2 * 32 + rq * 8 + hi * 4);
      float4 s3 = *(const float4*)(sxr + 3 * 32 + rq * 8 + hi * 4);
      p -= 2.0f * (acc0[rq * 4 + 0] * s0.x + acc0[rq * 4 + 1] * s0.y +
                   acc0[rq * 4 + 2] * s0.z + acc0[rq * 4 + 3] * s0.w +
                   acc1[rq * 4 + 0] * s1.x + acc1[rq * 4 + 1] * s1.y +
                   acc1[rq * 4 + 2] * s1.z + acc1[rq * 4 + 3] * s1.w +
                   acc2[rq * 4 + 0] * s2.x + acc2[rq * 4 + 1] * s2.y +
                   acc2[rq * 4 + 2] * s2.z + acc2[rq * 4 + 3] * s2.w +
                   acc3[rq * 4 + 0] * s3.x + acc3[rq * 4 + 1] * s3.y +
                   acc3[rq * 4 + 2] * s3.z + acc3[rq * 4 + 3] * s3.w);
    }
    if (hi == 0) p += accN[0] + accN[1] * nsub[i];   // d'=0: t2 partial, d'=1: rowsum
#pragma unroll
    for (int d = 1; d < 64; d <<= 1) p += __shfl_xor(p, d, 64);
    if (lane == 0) wsum[w] = p;
    __syncthreads();
    if (tid == 0) gpart[gid] = wsum[0] + wsum[1] + wsum[2] + wsum[3];
  } else {
    // ------------------ contrast ------------------
    int cid = base;
    int rt = cid >> 3, oct = cid & 7;
    int iwb = rt * 128 + w * 32;
    int i = iwb + il;
    int C0 = oct * 1024;
    s16x8 bf[8];
    {
      const char* rp = (const char*)hbf + (size_t)i * 256;
      int sw = (i & 7) << 4;
#pragma unroll
      for (int ks = 0; ks < 8; ++ks)
        bf[ks] = *(const s16x8*)(rp + ((ks * 32 + hi * 16) ^ sw));
    }
    float s = 0.f;
    auto stage = [&](int buf, int t) {
      const char* src = (const char*)hbf + (size_t)(C0 + t * 64) * 256;
      char* dst = (char*)&lds[buf][0];
#pragma unroll
      for (int j = 0; j < 4; ++j)
        gl16(src + j * 4096 + tid * 16, dst + j * 4096 + tid * 16);
    };
    stage(0, 0);
    __syncthreads();
    int cur = 0;
    for (int t = 0; t < 16; ++t) {
      if (t < 15) stage(cur ^ 1, t + 1);
      const char* basep = (const char*)&lds[cur][0];
      int jb0 = C0 + t * 64;
#pragma unroll
      for (int js = 0; js < 2; ++js) {
        int rl0 = js * 32 + il;
        const char* vb = basep + rl0 * 256;
        int sw = (rl0 & 7) << 4;
        f32x16 a = zero16();
#pragma unroll
        for (int ks = 0; ks < 8; ++ks) {
          s16x8 af = *(const s16x8*)(vb + ((ks * 32 + hi * 16) ^ sw));
          a = mfma32(af, bf[ks], a);
        }
        bool diag = (jb0 + js * 32 == iwb);   // wave-uniform
#pragma unroll
        for (int r = 0; r < 16; ++r) {
          float term = fexp2(a[r] - COFF);
          if (diag && ((r & 3) + 8 * (r >> 2) + 4 * hi == il)) term = 0.f;
          s += term;
        }
      }
      __syncthreads();
      cur ^= 1;
    }
    s += __shfl_xor(s, 32, 64);
    if (hi == 0) spart[oct * 8192 + i] = s;
  }
}

// =================== epilogue: lse + final deterministic sum =================
__global__ __launch_bounds__(1024)
void epilogue(const float* __restrict__ spart, const float* __restrict__ pos4,
              const float* __restrict__ gpart, float* __restrict__ out) {
  int tid = threadIdx.x, lane = tid & 63, w = tid >> 6;
  float csum = 0.f;
#pragma unroll
  for (int rr = 0; rr < 8; ++rr) {
    int row = rr * 1024 + tid;
    float S = 0.f;
#pragma unroll
    for (int o = 0; o < 8; ++o) S += spart[o * 8192 + row];
    csum += LN2F * (COFF + flog2(S)) - pos4[row & 4095];
  }
  double cd = (double)csum;
  double gd = (double)gpart[tid];
#pragma unroll
  for (int d = 1; d < 64; d <<= 1) {
    cd += __shfl_xor(cd, d, 64);
    gd += __shfl_xor(gd, d, 64);
  }
  __shared__ double wc[16], wg[16];
  if (lane == 0) { wc[w] = cd; wg[w] = gd; }
  __syncthreads();
  if (tid == 0) {
    double C = 0.0, Gs = 0.0;
#pragma unroll
    for (int k = 0; k < 16; ++k) { C += wc[k]; Gs += wg[k]; }
    out[0] = (float)(C / 8192.0 + Gs / (4096.0 * 8192.0));
  }
}

extern "C" void kernel_launch(void* const* d_in, const int* in_sizes, int n_in,
                              void* d_out, int out_size, void* d_ws, size_t ws_size,
                              hipStream_t stream) {
  const float* h_i = (const float*)d_in[0];
  const float* h_j = (const float*)d_in[1];
  const float* G   = (const float*)d_in[2];
  const float* sx  = (const float*)d_in[3];
  const float* ax  = (const float*)d_in[4];
  char* ws = (char*)d_ws;
  u16*   hbf   = (u16*)(ws);                    // 2,097,152 B
  u16*   axG   = (u16*)(ws + 2097152);          // 2,097,152 B (512 kc x 4KB)
  u16*   axN   = (u16*)(ws + 4194304);          //   524,288 B (512 kc x 1KB)
  float* nsub  = (float*)(ws + 4718592);        //    16,384 B
  float* pos4  = (float*)(ws + 4734976);        //    16,384 B
  float* spart = (float*)(ws + 4751360);        //   262,144 B (8 x 8192)
  float* gpart = (float*)(ws + 5013504);        //     4,096 B
  float* out = (float*)d_out;

  prep_all<<<dim3(656), dim3(256), 0, stream>>>(h_i, h_j, ax, sx, hbf, axG, axN, nsub, pos4);
  main_fused<<<dim3(1536), dim3(256), 0, stream>>>(G, sx, axG, axN, nsub, hbf, spart, gpart);
  epilogue<<<dim3(1), dim3(1024), 0, stream>>>(spart, pos4, gpart, out);
}